// Round 9
// baseline (224.490 us; speedup 1.0000x reference)
//
#include <hip/hip_runtime.h>

// ---------------------------------------------------------------------------
// GIN forward, bf16 node features, aggregation FUSED into the MLP kernels.
// d_out layout: [out (G*64) | h (N*64)]
// ws: [xb | Z0b (bf16 rows) | row_ptr | ebase | cursor | ghist | ebuf | hg]
// Bucket = dst >> 7.  Requires N < 65536 (ids pack u16).
// ---------------------------------------------------------------------------

#define EPB 2048
#define MAXB 512

__device__ __forceinline__ unsigned bf16pack(float a, float b) {
    unsigned ua = __float_as_uint(a);
    unsigned ub = __float_as_uint(b);
    ua = (ua + 0x7FFFu + ((ua >> 16) & 1u)) >> 16;
    ub = (ub + 0x7FFFu + ((ub >> 16) & 1u)) & 0xFFFF0000u;
    return ua | ub;
}
__device__ __forceinline__ float bf16lo(unsigned w) { return __uint_as_float(w << 16); }
__device__ __forceinline__ float bf16hi(unsigned w) { return __uint_as_float(w & 0xFFFF0000u); }

// ---- cast x -> bf16 rows, and zero the bucket histogram --------------------
__global__ __launch_bounds__(256) void cast_zero(uint4* __restrict__ xb4,
                                                 const float4* __restrict__ x4,
                                                 int nq, int* __restrict__ gh) {
    if (blockIdx.x == 0) {
        for (int i = threadIdx.x; i < MAXB; i += 256) gh[i] = 0;
    }
    int i = blockIdx.x * 256 + threadIdx.x;
    if (i >= nq) return;
    float4 a = x4[2 * i], b = x4[2 * i + 1];
    uint4 o;
    o.x = bf16pack(a.x, a.y); o.y = bf16pack(a.z, a.w);
    o.z = bf16pack(b.x, b.y); o.w = bf16pack(b.z, b.w);
    xb4[i] = o;
}

// ---- Phase A: global bucket histogram (LDS-aggregated) --------------------
__global__ __launch_bounds__(256) void bucket_hist(int* __restrict__ gh,
                                                   const int* __restrict__ dst,
                                                   int E) {
    __shared__ int h[MAXB];
    const int t = threadIdx.x;
    for (int i = t; i < MAXB; i += 256) h[i] = 0;
    __syncthreads();
    const int base = blockIdx.x * EPB;
#pragma unroll
    for (int i = 0; i < 8; ++i) {
        int e = base + i * 256 + t;
        if (e < E) atomicAdd(&h[dst[e] >> 7], 1);
    }
    __syncthreads();
    for (int i = t; i < MAXB; i += 256) {
        int v = h[i];
        if (v) atomicAdd(&gh[i], v);
    }
}

// ---- Phase B: single-block scan of bucket counts ---------------------------
__global__ __launch_bounds__(1024) void scan_small(const int* __restrict__ in,
                                                   int* __restrict__ ebase,
                                                   int* __restrict__ cursor,
                                                   int n, int total) {
    __shared__ int arr[1024];
    const int t = threadIdx.x;
    int v = (t < n) ? in[t] : 0;
    arr[t] = v;
    __syncthreads();
    for (int s = 1; s < 1024; s <<= 1) {
        int u = (t >= s) ? arr[t - s] : 0;
        __syncthreads();
        arr[t] += u;
        __syncthreads();
    }
    int excl = (t > 0) ? arr[t - 1] : 0;
    if (t < n) {
        ebase[t] = excl;
        cursor[t] = excl;
    }
    if (t == 0) ebase[n] = total;
}

// ---- Phase C: scatter packed (src<<16|dst) into bucket-grouped ebuf -------
__global__ __launch_bounds__(256) void bin_scatter(unsigned* __restrict__ ebuf,
                                                   int* __restrict__ cursor,
                                                   const int* __restrict__ src,
                                                   const int* __restrict__ dst,
                                                   int E) {
    __shared__ int h[MAXB];
    __shared__ int gb[MAXB];
    const int t = threadIdx.x;
    for (int i = t; i < MAXB; i += 256) h[i] = 0;
    __syncthreads();
    const int base = blockIdx.x * EPB;
    int sv[8], dv[8];
#pragma unroll
    for (int i = 0; i < 8; ++i) {
        int e = base + i * 256 + t;
        if (e < E) {
            sv[i] = src[e];
            dv[i] = dst[e];
            atomicAdd(&h[dv[i] >> 7], 1);
        } else {
            dv[i] = -1;
        }
    }
    __syncthreads();
    for (int i = t; i < MAXB; i += 256) {
        int v = h[i];
        gb[i] = v ? atomicAdd(&cursor[i], v) : 0;
        h[i] = 0;
    }
    __syncthreads();
#pragma unroll
    for (int i = 0; i < 8; ++i) {
        if (dv[i] >= 0) {
            int b = dv[i] >> 7;
            int p = atomicAdd(&h[b], 1);
            ebuf[gb[b] + p] = ((unsigned)sv[i] << 16) | (unsigned)dv[i];
        }
    }
}

// ---- Phase D: per-bucket row_ptr + in-place col fill (LDS-staged) ---------
__global__ __launch_bounds__(256) void bucket_fill(unsigned* __restrict__ ebuf,
                                                   const int* __restrict__ ebase,
                                                   int* __restrict__ row_ptr,
                                                   int N, int E) {
    __shared__ unsigned pairLDS[4096];
    __shared__ unsigned colLDS[4096];
    __shared__ int deg[128], off[128], cur[128];
    const int b = blockIdx.x;
    const int t = threadIdx.x;
    const int lo = ebase[b];
    const int hi = ebase[b + 1];
    const int m = hi - lo;
    const int nb0 = b << 7;

    if (t < 128) deg[t] = 0;
    __syncthreads();
    for (int k = t; k < m; k += 256) {
        unsigned v = ebuf[lo + k];
        pairLDS[k] = v;
        atomicAdd(&deg[(int)(v & 0xFFFFu) - nb0], 1);
    }
    __syncthreads();
    if (t < 128) off[t] = deg[t];
    __syncthreads();
    for (int s = 1; s < 128; s <<= 1) {
        int u = 0;
        if (t < 128 && t >= s) u = off[t - s];
        __syncthreads();
        if (t < 128) off[t] += u;
        __syncthreads();
    }
    if (t < 128) {
        int excl = off[t] - deg[t];
        cur[t] = excl;
        int node = nb0 + t;
        if (node <= N) row_ptr[node] = lo + excl;
    }
    __syncthreads();
    for (int k = t; k < m; k += 256) {
        unsigned v = pairLDS[k];
        int dl = (int)(v & 0xFFFFu) - nb0;
        int p = atomicAdd(&cur[dl], 1);
        colLDS[p] = v >> 16;
    }
    __syncthreads();
    for (int k = t; k < m; k += 256) ebuf[lo + k] = colLDS[k];
}

// ---- FUSED aggregate + MLP ------------------------------------------------
// Block = 64 nodes. Wave w gathers nodes w*16..w*16+15 straight into the
// transposed LDS tile (f32), then the block runs the register-tiled GEMM(s),
// fused double-BN affine + relu, and stores bf16 (layer0) or f32 (layer1).
template <bool TWO, bool OUTB>
__global__ __launch_bounds__(256) void mlp_agg(
    const unsigned* __restrict__ inb, unsigned* __restrict__ outb,
    float* __restrict__ outf,
    const int* __restrict__ row_ptr, const unsigned* __restrict__ col,
    const float* __restrict__ eps, int N,
    const float* __restrict__ Wa, const float* __restrict__ ba,
    const float* __restrict__ Wb, const float* __restrict__ bb,
    const float* __restrict__ gi, const float* __restrict__ bei,
    const float* __restrict__ mi, const float* __restrict__ vi,
    const float* __restrict__ go, const float* __restrict__ beo,
    const float* __restrict__ mo, const float* __restrict__ vo) {
    constexpr int PITCH = 68;
    __shared__ __align__(16) float Ws1[64 * 64];
    __shared__ __align__(16) float Ws2[TWO ? 64 * 64 : 4];
    __shared__ __align__(16) float XY[64 * PITCH];  // Xs, later aliased as Ys

    const int t = threadIdx.x;
    const int row0 = blockIdx.x * 64;

    // ---- stage weights (overlaps with the gather below) ----
#pragma unroll
    for (int j = 0; j < 4; ++j) {
        int f4 = t + 256 * j;
        reinterpret_cast<float4*>(Ws1)[f4] = reinterpret_cast<const float4*>(Wa)[f4];
        if (TWO)
            reinterpret_cast<float4*>(Ws2)[f4] = reinterpret_cast<const float4*>(Wb)[f4];
    }

    // ---- fused aggregation into XY (transposed, f32) ----
    {
        const int lane = t & 63;
        const int w = t >> 6;
        const int q = lane & 7;   // 16B chunk (k = q*8 .. q*8+7)
        const int jj = lane >> 3; // neighbor slot 0..7
        const uint4* in4 = reinterpret_cast<const uint4*>(inb);
        const float s = 1.0f + eps[0];
        for (int it = 0; it < 16; ++it) {
            const int r = w * 16 + it;
            const int n = row0 + r;
            float a[8];
#pragma unroll
            for (int k2 = 0; k2 < 8; ++k2) a[k2] = 0.f;
            if (n < N) {
                const int lo = row_ptr[n];
                const int hi = row_ptr[n + 1];
                int j = lo;
                for (; j + 8 <= hi; j += 8) {
                    unsigned c = col[j + jj];
                    uint4 v = in4[(size_t)c * 8 + q];
                    a[0] += bf16lo(v.x); a[1] += bf16hi(v.x);
                    a[2] += bf16lo(v.y); a[3] += bf16hi(v.y);
                    a[4] += bf16lo(v.z); a[5] += bf16hi(v.z);
                    a[6] += bf16lo(v.w); a[7] += bf16hi(v.w);
                }
                if (j + jj < hi) {
                    unsigned c = col[j + jj];
                    uint4 v = in4[(size_t)c * 8 + q];
                    a[0] += bf16lo(v.x); a[1] += bf16hi(v.x);
                    a[2] += bf16lo(v.y); a[3] += bf16hi(v.y);
                    a[4] += bf16lo(v.z); a[5] += bf16hi(v.z);
                    a[6] += bf16lo(v.w); a[7] += bf16hi(v.w);
                }
            }
#pragma unroll
            for (int k2 = 0; k2 < 8; ++k2) {
                a[k2] += __shfl_xor(a[k2], 8);
                a[k2] += __shfl_xor(a[k2], 16);
                a[k2] += __shfl_xor(a[k2], 32);
            }
            if (jj == 0) {
                if (n < N) {
                    uint4 o = in4[(size_t)n * 8 + q];
                    a[0] = fmaf(s, bf16lo(o.x), a[0]); a[1] = fmaf(s, bf16hi(o.x), a[1]);
                    a[2] = fmaf(s, bf16lo(o.y), a[2]); a[3] = fmaf(s, bf16hi(o.y), a[3]);
                    a[4] = fmaf(s, bf16lo(o.z), a[4]); a[5] = fmaf(s, bf16hi(o.z), a[5]);
                    a[6] = fmaf(s, bf16lo(o.w), a[6]); a[7] = fmaf(s, bf16hi(o.w), a[7]);
                }
                // staggered store: lanes q=0..7 hit 8 distinct banks each step
#pragma unroll
                for (int j2 = 0; j2 < 8; ++j2) {
                    int jw = (j2 + q) & 7;
                    XY[(q * 8 + jw) * PITCH + r] = a[jw];
                }
            }
        }
    }
    __syncthreads();

    const int tr = t >> 4;
    const int tc = t & 15;

    float acc[4][4];
#pragma unroll
    for (int i = 0; i < 4; ++i)
#pragma unroll
        for (int j = 0; j < 4; ++j) acc[i][j] = 0.f;

#pragma unroll 4
    for (int k = 0; k < 64; ++k) {
        float4 a = *reinterpret_cast<const float4*>(&XY[k * PITCH + 4 * tr]);
        float4 b = *reinterpret_cast<const float4*>(&Ws1[k * 64 + 4 * tc]);
        float av[4] = {a.x, a.y, a.z, a.w};
        float bv[4] = {b.x, b.y, b.z, b.w};
#pragma unroll
        for (int i = 0; i < 4; ++i)
#pragma unroll
            for (int j = 0; j < 4; ++j) acc[i][j] = fmaf(av[i], bv[j], acc[i][j]);
    }

    float u[4][4];
#pragma unroll
    for (int i = 0; i < 4; ++i)
#pragma unroll
        for (int j = 0; j < 4; ++j)
            u[i][j] = fmaxf(acc[i][j] + ba[4 * tc + j], 0.f);

    if (TWO) {
        __syncthreads();  // everyone done reading XY as Xs
#pragma unroll
        for (int j = 0; j < 4; ++j) {
            float4 w = make_float4(u[0][j], u[1][j], u[2][j], u[3][j]);
            *reinterpret_cast<float4*>(&XY[(4 * tc + j) * PITCH + 4 * tr]) = w;
        }
        __syncthreads();
#pragma unroll
        for (int i = 0; i < 4; ++i)
#pragma unroll
            for (int j = 0; j < 4; ++j) acc[i][j] = 0.f;
#pragma unroll 4
        for (int k = 0; k < 64; ++k) {
            float4 a = *reinterpret_cast<const float4*>(&XY[k * PITCH + 4 * tr]);
            float4 b = *reinterpret_cast<const float4*>(&Ws2[k * 64 + 4 * tc]);
            float av[4] = {a.x, a.y, a.z, a.w};
            float bv[4] = {b.x, b.y, b.z, b.w};
#pragma unroll
            for (int i = 0; i < 4; ++i)
#pragma unroll
                for (int j = 0; j < 4; ++j) acc[i][j] = fmaf(av[i], bv[j], acc[i][j]);
        }
#pragma unroll
        for (int i = 0; i < 4; ++i)
#pragma unroll
            for (int j = 0; j < 4; ++j)
                u[i][j] = fmaxf(acc[i][j] + bb[4 * tc + j], 0.f);
    }

    float sc[4], sh[4];
#pragma unroll
    for (int j = 0; j < 4; ++j) {
        int c = 4 * tc + j;
        float si = gi[c] * rsqrtf(vi[c] + 1e-5f);
        float ti = bei[c] - mi[c] * si;
        float so = go[c] * rsqrtf(vo[c] + 1e-5f);
        float to = beo[c] - mo[c] * so;
        sc[j] = si * so;
        sh[j] = ti * so + to;
    }
#pragma unroll
    for (int i = 0; i < 4; ++i) {
        int grow = row0 + 4 * tr + i;
        if (grow >= N) continue;
        float y0 = fmaxf(u[i][0] * sc[0] + sh[0], 0.f);
        float y1 = fmaxf(u[i][1] * sc[1] + sh[1], 0.f);
        float y2 = fmaxf(u[i][2] * sc[2] + sh[2], 0.f);
        float y3 = fmaxf(u[i][3] * sc[3] + sh[3], 0.f);
        if (OUTB) {
            uint2 w;
            w.x = bf16pack(y0, y1);
            w.y = bf16pack(y2, y3);
            *reinterpret_cast<uint2*>(outb + (size_t)grow * 32 + tc * 2) = w;
        } else {
            float4 w = make_float4(y0, y1, y2, y3);
            *reinterpret_cast<float4*>(outf + (size_t)grow * 64 + 4 * tc) = w;
        }
    }
}

__device__ __forceinline__ int lbound(const int* __restrict__ a, int n, int v) {
    int lo = 0, hi = n;
    while (lo < hi) {
        int mid = (lo + hi) >> 1;
        if (a[mid] < v) lo = mid + 1;
        else hi = mid;
    }
    return lo;
}

// ---- per-graph mean -------------------------------------------------------
__global__ __launch_bounds__(256) void graph_mean(const float* __restrict__ H,
                                                  const int* __restrict__ gid,
                                                  int N,
                                                  float* __restrict__ hg) {
    __shared__ float part[4][64];
    const int g = blockIdx.x;
    const int lane = threadIdx.x & 63;
    const int w = threadIdx.x >> 6;
    const int lo = lbound(gid, N, g);
    const int hi = lbound(gid, N, g + 1);
    float acc = 0.f;
    for (int r = lo + w; r < hi; r += 4) acc += H[(size_t)r * 64 + lane];
    part[w][lane] = acc;
    __syncthreads();
    if (w == 0) {
        float s = part[0][lane] + part[1][lane] + part[2][lane] + part[3][lane];
        float cnt = fmaxf((float)(hi - lo), 1.0f);
        hg[(size_t)g * 64 + lane] = s / cnt;
    }
}

// ---- readout MLP ------------------------------------------------------------
__global__ __launch_bounds__(256) void readout_mlp(
    const float* __restrict__ hg, int G,
    const float* __restrict__ W1, const float* __restrict__ b1,
    const float* __restrict__ W2, const float* __restrict__ b2,
    float* __restrict__ out) {
    constexpr int PITCH = 68;
    __shared__ __align__(16) float Ws1[64 * 64];
    __shared__ __align__(16) float Ws2[64 * 64];
    __shared__ __align__(16) float Xs[64 * PITCH];
    __shared__ __align__(16) float Ys[64 * PITCH];

    const int t = threadIdx.x;
    const int row0 = blockIdx.x * 64;

#pragma unroll
    for (int j = 0; j < 4; ++j) {
        int f4 = t + 256 * j;
        reinterpret_cast<float4*>(Ws1)[f4] = reinterpret_cast<const float4*>(W1)[f4];
        reinterpret_cast<float4*>(Ws2)[f4] = reinterpret_cast<const float4*>(W2)[f4];
    }
    {
        int rs = t >> 2;
        int kq = t & 3;
        int grow = row0 + rs;
#pragma unroll
        for (int j = 0; j < 4; ++j) {
            int cf4 = kq + 4 * j;
            float4 v = make_float4(0.f, 0.f, 0.f, 0.f);
            if (grow < G)
                v = *reinterpret_cast<const float4*>(hg + (size_t)grow * 64 + cf4 * 4);
            int kb = cf4 * 4;
            Xs[(kb + 0) * PITCH + rs] = v.x;
            Xs[(kb + 1) * PITCH + rs] = v.y;
            Xs[(kb + 2) * PITCH + rs] = v.z;
            Xs[(kb + 3) * PITCH + rs] = v.w;
        }
    }
    __syncthreads();

    const int tr = t >> 4;
    const int tc = t & 15;

    float acc[4][4];
#pragma unroll
    for (int i = 0; i < 4; ++i)
#pragma unroll
        for (int j = 0; j < 4; ++j) acc[i][j] = 0.f;
#pragma unroll 4
    for (int k = 0; k < 64; ++k) {
        float4 a = *reinterpret_cast<const float4*>(&Xs[k * PITCH + 4 * tr]);
        float4 b = *reinterpret_cast<const float4*>(&Ws1[k * 64 + 4 * tc]);
        float av[4] = {a.x, a.y, a.z, a.w};
        float bv[4] = {b.x, b.y, b.z, b.w};
#pragma unroll
        for (int i = 0; i < 4; ++i)
#pragma unroll
            for (int j = 0; j < 4; ++j) acc[i][j] = fmaf(av[i], bv[j], acc[i][j]);
    }
    float u[4][4];
#pragma unroll
    for (int i = 0; i < 4; ++i)
#pragma unroll
        for (int j = 0; j < 4; ++j)
            u[i][j] = fmaxf(acc[i][j] + b1[4 * tc + j], 0.f);

#pragma unroll
    for (int j = 0; j < 4; ++j) {
        float4 w = make_float4(u[0][j], u[1][j], u[2][j], u[3][j]);
        *reinterpret_cast<float4*>(&Ys[(4 * tc + j) * PITCH + 4 * tr]) = w;
    }
    __syncthreads();
#pragma unroll
    for (int i = 0; i < 4; ++i)
#pragma unroll
        for (int j = 0; j < 4; ++j) acc[i][j] = 0.f;
#pragma unroll 4
    for (int k = 0; k < 64; ++k) {
        float4 a = *reinterpret_cast<const float4*>(&Ys[k * PITCH + 4 * tr]);
        float4 b = *reinterpret_cast<const float4*>(&Ws2[k * 64 + 4 * tc]);
        float av[4] = {a.x, a.y, a.z, a.w};
        float bv[4] = {b.x, b.y, b.z, b.w};
#pragma unroll
        for (int i = 0; i < 4; ++i)
#pragma unroll
            for (int j = 0; j < 4; ++j) acc[i][j] = fmaf(av[i], bv[j], acc[i][j]);
    }
#pragma unroll
    for (int i = 0; i < 4; ++i) {
        int grow = row0 + 4 * tr + i;
        if (grow >= G) continue;
        float4 w;
        w.x = acc[i][0] + b2[4 * tc + 0];
        w.y = acc[i][1] + b2[4 * tc + 1];
        w.z = acc[i][2] + b2[4 * tc + 2];
        w.w = acc[i][3] + b2[4 * tc + 3];
        *reinterpret_cast<float4*>(out + (size_t)grow * 64 + 4 * tc) = w;
    }
}

extern "C" void kernel_launch(void* const* d_in, const int* in_sizes, int n_in,
                              void* d_out, int out_size, void* d_ws, size_t ws_size,
                              hipStream_t stream) {
    const float* x    = (const float*)d_in[0];
    const int*   src  = (const int*)d_in[1];
    const int*   dst  = (const int*)d_in[2];
    const int*   gid  = (const int*)d_in[3];
    const float* eps0 = (const float*)d_in[4];
    const float* W0a  = (const float*)d_in[5];
    const float* bb0a = (const float*)d_in[6];
    const float* W0b  = (const float*)d_in[7];
    const float* bb0b = (const float*)d_in[8];
    const float* g0i  = (const float*)d_in[9];
    const float* be0i = (const float*)d_in[10];
    const float* m0i  = (const float*)d_in[11];
    const float* v0i  = (const float*)d_in[12];
    const float* g0   = (const float*)d_in[13];
    const float* be0  = (const float*)d_in[14];
    const float* m0   = (const float*)d_in[15];
    const float* v0   = (const float*)d_in[16];
    const float* eps1 = (const float*)d_in[17];
    const float* W1a  = (const float*)d_in[18];
    const float* bb1a = (const float*)d_in[19];
    const float* g1i  = (const float*)d_in[20];
    const float* be1i = (const float*)d_in[21];
    const float* m1i  = (const float*)d_in[22];
    const float* v1i  = (const float*)d_in[23];
    const float* g1   = (const float*)d_in[24];
    const float* be1  = (const float*)d_in[25];
    const float* m1   = (const float*)d_in[26];
    const float* v1   = (const float*)d_in[27];
    const float* Wr1  = (const float*)d_in[28];
    const float* br1  = (const float*)d_in[29];
    const float* Wr2  = (const float*)d_in[30];
    const float* br2  = (const float*)d_in[31];

    const int N = in_sizes[0] / 64;       // 50000
    const int E = in_sizes[1];            // 800000
    const int G = out_size / 64 - N;      // 500
    const int NB = (N + 127) >> 7;

    // ws layout
    char* ws = (char*)d_ws;
    unsigned* xb      = (unsigned*)ws;     ws += (size_t)N * 32 * 4;
    unsigned* Z0b     = (unsigned*)ws;     ws += (size_t)N * 32 * 4;
    int*      row_ptr = (int*)ws;          ws += ((size_t)N + 8) * 4;
    int*      ebase   = (int*)ws;          ws += (MAXB + 4) * 4;
    int*      cursor  = (int*)ws;          ws += (MAXB + 4) * 4;
    int*      ghist   = (int*)ws;          ws += (MAXB + 4) * 4;
    unsigned* ebuf    = (unsigned*)ws;     ws += (size_t)E * 4;
    float*    hg      = (float*)ws;        // G*64

    float* OUT = (float*)d_out;
    float* H   = OUT + (size_t)G * 64;

    const int EB = (E + EPB - 1) / EPB;
    const int NQ = N * 8;

    // ---- cast x->bf16 + zero hist ----
    cast_zero<<<(NQ + 255) / 256, 256, 0, stream>>>(
        (uint4*)xb, (const float4*)x, NQ, ghist);

    // ---- build CSR (bucketed; shared by both layers) ----
    bucket_hist<<<EB, 256, 0, stream>>>(ghist, dst, E);
    scan_small<<<1, 1024, 0, stream>>>(ghist, ebase, cursor, NB, E);
    bin_scatter<<<EB, 256, 0, stream>>>(ebuf, cursor, src, dst, E);
    bucket_fill<<<NB, 256, 0, stream>>>(ebuf, ebase, row_ptr, N, E);

    // ---- GIN layer 0 (fused aggregate + MLP) ----
    mlp_agg<true, true><<<(N + 63) / 64, 256, 0, stream>>>(
        xb, Z0b, nullptr, row_ptr, ebuf, eps0, N,
        W0a, bb0a, W0b, bb0b, g0i, be0i, m0i, v0i, g0, be0, m0, v0);

    // ---- GIN layer 1 (fused aggregate + MLP) ----
    mlp_agg<false, false><<<(N + 63) / 64, 256, 0, stream>>>(
        Z0b, nullptr, H, row_ptr, ebuf, eps1, N,
        W1a, bb1a, nullptr, nullptr, g1i, be1i, m1i, v1i, g1, be1, m1, v1);

    // ---- readout ----
    graph_mean<<<G, 256, 0, stream>>>(H, gid, N, hg);
    readout_mlp<<<(G + 63) / 64, 256, 0, stream>>>(hg, G, Wr1, br1, Wr2, br2, OUT);
}

// Round 10
// 149.160 us; speedup vs baseline: 1.5050x; 1.5050x over previous
//
#include <hip/hip_runtime.h>

// ---------------------------------------------------------------------------
// GIN forward, bf16 node-feature intermediates (f32 math, f32 outputs).
// Separate high-TLP gather kernels + LDS-tiled MLP kernels (R8 structure;
// R9's gather-into-MLP fusion regressed: gather needs wave count, not LDS).
// d_out layout: [out (G*64) | h (N*64)]
// ws: [xb | Ab | Z0b | Bb | row_ptr | ebase | cursor | ghist | ebuf | hg]
// Bucket = dst >> 7.  Requires N < 65536 (ids pack u16).
// ---------------------------------------------------------------------------

#define EPB 2048
#define MAXB 512

__device__ __forceinline__ unsigned bf16pack(float a, float b) {
    unsigned ua = __float_as_uint(a);
    unsigned ub = __float_as_uint(b);
    ua = (ua + 0x7FFFu + ((ua >> 16) & 1u)) >> 16;
    ub = (ub + 0x7FFFu + ((ub >> 16) & 1u)) & 0xFFFF0000u;
    return ua | ub;
}
__device__ __forceinline__ float bf16lo(unsigned w) { return __uint_as_float(w << 16); }
__device__ __forceinline__ float bf16hi(unsigned w) { return __uint_as_float(w & 0xFFFF0000u); }

// ---- cast x -> bf16 rows, and zero the bucket histogram --------------------
__global__ __launch_bounds__(256) void cast_zero(uint4* __restrict__ xb4,
                                                 const float4* __restrict__ x4,
                                                 int nq, int* __restrict__ gh) {
    if (blockIdx.x == 0) {
        for (int i = threadIdx.x; i < MAXB; i += 256) gh[i] = 0;
    }
    int i = blockIdx.x * 256 + threadIdx.x;
    if (i >= nq) return;
    float4 a = x4[2 * i], b = x4[2 * i + 1];
    uint4 o;
    o.x = bf16pack(a.x, a.y); o.y = bf16pack(a.z, a.w);
    o.z = bf16pack(b.x, b.y); o.w = bf16pack(b.z, b.w);
    xb4[i] = o;
}

// ---- Phase A: global bucket histogram (LDS-aggregated) --------------------
__global__ __launch_bounds__(256) void bucket_hist(int* __restrict__ gh,
                                                   const int* __restrict__ dst,
                                                   int E) {
    __shared__ int h[MAXB];
    const int t = threadIdx.x;
    for (int i = t; i < MAXB; i += 256) h[i] = 0;
    __syncthreads();
    const int base = blockIdx.x * EPB;
#pragma unroll
    for (int i = 0; i < 8; ++i) {
        int e = base + i * 256 + t;
        if (e < E) atomicAdd(&h[dst[e] >> 7], 1);
    }
    __syncthreads();
    for (int i = t; i < MAXB; i += 256) {
        int v = h[i];
        if (v) atomicAdd(&gh[i], v);
    }
}

// ---- Phase B: single-block scan of bucket counts ---------------------------
__global__ __launch_bounds__(1024) void scan_small(const int* __restrict__ in,
                                                   int* __restrict__ ebase,
                                                   int* __restrict__ cursor,
                                                   int n, int total) {
    __shared__ int arr[1024];
    const int t = threadIdx.x;
    int v = (t < n) ? in[t] : 0;
    arr[t] = v;
    __syncthreads();
    for (int s = 1; s < 1024; s <<= 1) {
        int u = (t >= s) ? arr[t - s] : 0;
        __syncthreads();
        arr[t] += u;
        __syncthreads();
    }
    int excl = (t > 0) ? arr[t - 1] : 0;
    if (t < n) {
        ebase[t] = excl;
        cursor[t] = excl;
    }
    if (t == 0) ebase[n] = total;
}

// ---- Phase C: scatter packed (src<<16|dst) into bucket-grouped ebuf -------
__global__ __launch_bounds__(256) void bin_scatter(unsigned* __restrict__ ebuf,
                                                   int* __restrict__ cursor,
                                                   const int* __restrict__ src,
                                                   const int* __restrict__ dst,
                                                   int E) {
    __shared__ int h[MAXB];
    __shared__ int gb[MAXB];
    const int t = threadIdx.x;
    for (int i = t; i < MAXB; i += 256) h[i] = 0;
    __syncthreads();
    const int base = blockIdx.x * EPB;
    int sv[8], dv[8];
#pragma unroll
    for (int i = 0; i < 8; ++i) {
        int e = base + i * 256 + t;
        if (e < E) {
            sv[i] = src[e];
            dv[i] = dst[e];
            atomicAdd(&h[dv[i] >> 7], 1);
        } else {
            dv[i] = -1;
        }
    }
    __syncthreads();
    for (int i = t; i < MAXB; i += 256) {
        int v = h[i];
        gb[i] = v ? atomicAdd(&cursor[i], v) : 0;
        h[i] = 0;
    }
    __syncthreads();
#pragma unroll
    for (int i = 0; i < 8; ++i) {
        if (dv[i] >= 0) {
            int b = dv[i] >> 7;
            int p = atomicAdd(&h[b], 1);
            ebuf[gb[b] + p] = ((unsigned)sv[i] << 16) | (unsigned)dv[i];
        }
    }
}

// ---- Phase D: per-bucket row_ptr + in-place col fill (LDS-staged) ---------
__global__ __launch_bounds__(256) void bucket_fill(unsigned* __restrict__ ebuf,
                                                   const int* __restrict__ ebase,
                                                   int* __restrict__ row_ptr,
                                                   int N, int E) {
    __shared__ unsigned pairLDS[4096];
    __shared__ unsigned colLDS[4096];
    __shared__ int deg[128], off[128], cur[128];
    const int b = blockIdx.x;
    const int t = threadIdx.x;
    const int lo = ebase[b];
    const int hi = ebase[b + 1];
    const int m = hi - lo;
    const int nb0 = b << 7;

    if (t < 128) deg[t] = 0;
    __syncthreads();
    for (int k = t; k < m; k += 256) {
        unsigned v = ebuf[lo + k];
        pairLDS[k] = v;
        atomicAdd(&deg[(int)(v & 0xFFFFu) - nb0], 1);
    }
    __syncthreads();
    if (t < 128) off[t] = deg[t];
    __syncthreads();
    for (int s = 1; s < 128; s <<= 1) {
        int u = 0;
        if (t < 128 && t >= s) u = off[t - s];
        __syncthreads();
        if (t < 128) off[t] += u;
        __syncthreads();
    }
    if (t < 128) {
        int excl = off[t] - deg[t];
        cur[t] = excl;
        int node = nb0 + t;
        if (node <= N) row_ptr[node] = lo + excl;
    }
    __syncthreads();
    for (int k = t; k < m; k += 256) {
        unsigned v = pairLDS[k];
        int dl = (int)(v & 0xFFFFu) - nb0;
        int p = atomicAdd(&cur[dl], 1);
        colLDS[p] = v >> 16;
    }
    __syncthreads();
    for (int k = t; k < m; k += 256) ebuf[lo + k] = colLDS[k];
}

// ---- gather aggregation on bf16 rows: out = (1+eps)*in[n] + sum in[nbr] ---
// One wave per node (max TLP — this phase is LLC-latency bound).
__global__ __launch_bounds__(256) void aggregate_bf16(
    unsigned* __restrict__ outb, const unsigned* __restrict__ inb,
    const int* __restrict__ row_ptr, const unsigned* __restrict__ col,
    const float* __restrict__ eps, int N) {
    const int n = blockIdx.x * 4 + (threadIdx.x >> 6);
    if (n >= N) return;
    const int lane = threadIdx.x & 63;
    const int q = lane & 7;
    const int jj = lane >> 3;
    const int lo = row_ptr[n];
    const int hi = row_ptr[n + 1];
    const uint4* in4 = reinterpret_cast<const uint4*>(inb);

    float a[8];
#pragma unroll
    for (int k = 0; k < 8; ++k) a[k] = 0.f;

    int j = lo;
#pragma unroll 2
    for (; j + 8 <= hi; j += 8) {
        unsigned c = col[j + jj];
        uint4 v = in4[(size_t)c * 8 + q];
        a[0] += bf16lo(v.x); a[1] += bf16hi(v.x);
        a[2] += bf16lo(v.y); a[3] += bf16hi(v.y);
        a[4] += bf16lo(v.z); a[5] += bf16hi(v.z);
        a[6] += bf16lo(v.w); a[7] += bf16hi(v.w);
    }
    if (j + jj < hi) {
        unsigned c = col[j + jj];
        uint4 v = in4[(size_t)c * 8 + q];
        a[0] += bf16lo(v.x); a[1] += bf16hi(v.x);
        a[2] += bf16lo(v.y); a[3] += bf16hi(v.y);
        a[4] += bf16lo(v.z); a[5] += bf16hi(v.z);
        a[6] += bf16lo(v.w); a[7] += bf16hi(v.w);
    }

#pragma unroll
    for (int k = 0; k < 8; ++k) {
        a[k] += __shfl_xor(a[k], 8);
        a[k] += __shfl_xor(a[k], 16);
        a[k] += __shfl_xor(a[k], 32);
    }

    if (jj == 0) {
        float s = 1.0f + eps[0];
        uint4 o = in4[(size_t)n * 8 + q];
        a[0] = fmaf(s, bf16lo(o.x), a[0]); a[1] = fmaf(s, bf16hi(o.x), a[1]);
        a[2] = fmaf(s, bf16lo(o.y), a[2]); a[3] = fmaf(s, bf16hi(o.y), a[3]);
        a[4] = fmaf(s, bf16lo(o.z), a[4]); a[5] = fmaf(s, bf16hi(o.z), a[5]);
        a[6] = fmaf(s, bf16lo(o.w), a[6]); a[7] = fmaf(s, bf16hi(o.w), a[7]);
        uint4 w;
        w.x = bf16pack(a[0], a[1]); w.y = bf16pack(a[2], a[3]);
        w.z = bf16pack(a[4], a[5]); w.w = bf16pack(a[6], a[7]);
        reinterpret_cast<uint4*>(outb)[(size_t)n * 8 + q] = w;
    }
}

// ---- fused GIN MLP: bf16 in, f32 math, bf16 or f32 out ---------------------
// XY buffer aliased for Xs and Ys (sync-separated) -> 49KB LDS, 3 blocks/CU.
template <bool TWO, bool OUTB>
__global__ __launch_bounds__(256) void mlp_fused(
    const unsigned* __restrict__ inb, unsigned* __restrict__ outb,
    float* __restrict__ outf, int N,
    const float* __restrict__ Wa, const float* __restrict__ ba,
    const float* __restrict__ Wb, const float* __restrict__ bb,
    const float* __restrict__ gi, const float* __restrict__ bei,
    const float* __restrict__ mi, const float* __restrict__ vi,
    const float* __restrict__ go, const float* __restrict__ beo,
    const float* __restrict__ mo, const float* __restrict__ vo) {
    constexpr int PITCH = 68;
    __shared__ __align__(16) float Ws1[64 * 64];
    __shared__ __align__(16) float Ws2[TWO ? 64 * 64 : 4];
    __shared__ __align__(16) float XY[64 * PITCH];

    const int t = threadIdx.x;
    const int row0 = blockIdx.x * 64;

#pragma unroll
    for (int j = 0; j < 4; ++j) {
        int f4 = t + 256 * j;
        reinterpret_cast<float4*>(Ws1)[f4] = reinterpret_cast<const float4*>(Wa)[f4];
        if (TWO)
            reinterpret_cast<float4*>(Ws2)[f4] = reinterpret_cast<const float4*>(Wb)[f4];
    }
    {
        int rs = t >> 2;
        int kq = t & 3;
        int grow = row0 + rs;
        const uint4* in4 = reinterpret_cast<const uint4*>(inb);
#pragma unroll
        for (int jj = 0; jj < 2; ++jj) {
            int u4 = kq * 2 + jj;
            uint4 v = make_uint4(0u, 0u, 0u, 0u);
            if (grow < N) v = in4[(size_t)grow * 8 + u4];
            int kb = u4 * 8;
            XY[(kb + 0) * PITCH + rs] = bf16lo(v.x);
            XY[(kb + 1) * PITCH + rs] = bf16hi(v.x);
            XY[(kb + 2) * PITCH + rs] = bf16lo(v.y);
            XY[(kb + 3) * PITCH + rs] = bf16hi(v.y);
            XY[(kb + 4) * PITCH + rs] = bf16lo(v.z);
            XY[(kb + 5) * PITCH + rs] = bf16hi(v.z);
            XY[(kb + 6) * PITCH + rs] = bf16lo(v.w);
            XY[(kb + 7) * PITCH + rs] = bf16hi(v.w);
        }
    }
    __syncthreads();

    const int tr = t >> 4;
    const int tc = t & 15;

    float acc[4][4];
#pragma unroll
    for (int i = 0; i < 4; ++i)
#pragma unroll
        for (int j = 0; j < 4; ++j) acc[i][j] = 0.f;

#pragma unroll 4
    for (int k = 0; k < 64; ++k) {
        float4 a = *reinterpret_cast<const float4*>(&XY[k * PITCH + 4 * tr]);
        float4 b = *reinterpret_cast<const float4*>(&Ws1[k * 64 + 4 * tc]);
        float av[4] = {a.x, a.y, a.z, a.w};
        float bv[4] = {b.x, b.y, b.z, b.w};
#pragma unroll
        for (int i = 0; i < 4; ++i)
#pragma unroll
            for (int j = 0; j < 4; ++j) acc[i][j] = fmaf(av[i], bv[j], acc[i][j]);
    }

    float u[4][4];
#pragma unroll
    for (int i = 0; i < 4; ++i)
#pragma unroll
        for (int j = 0; j < 4; ++j)
            u[i][j] = fmaxf(acc[i][j] + ba[4 * tc + j], 0.f);

    if (TWO) {
        __syncthreads();  // all threads done reading XY as Xs
#pragma unroll
        for (int j = 0; j < 4; ++j) {
            float4 w = make_float4(u[0][j], u[1][j], u[2][j], u[3][j]);
            *reinterpret_cast<float4*>(&XY[(4 * tc + j) * PITCH + 4 * tr]) = w;
        }
        __syncthreads();
#pragma unroll
        for (int i = 0; i < 4; ++i)
#pragma unroll
            for (int j = 0; j < 4; ++j) acc[i][j] = 0.f;
#pragma unroll 4
        for (int k = 0; k < 64; ++k) {
            float4 a = *reinterpret_cast<const float4*>(&XY[k * PITCH + 4 * tr]);
            float4 b = *reinterpret_cast<const float4*>(&Ws2[k * 64 + 4 * tc]);
            float av[4] = {a.x, a.y, a.z, a.w};
            float bv[4] = {b.x, b.y, b.z, b.w};
#pragma unroll
            for (int i = 0; i < 4; ++i)
#pragma unroll
                for (int j = 0; j < 4; ++j) acc[i][j] = fmaf(av[i], bv[j], acc[i][j]);
        }
#pragma unroll
        for (int i = 0; i < 4; ++i)
#pragma unroll
            for (int j = 0; j < 4; ++j)
                u[i][j] = fmaxf(acc[i][j] + bb[4 * tc + j], 0.f);
    }

    float sc[4], sh[4];
#pragma unroll
    for (int j = 0; j < 4; ++j) {
        int c = 4 * tc + j;
        float si = gi[c] * rsqrtf(vi[c] + 1e-5f);
        float ti = bei[c] - mi[c] * si;
        float so = go[c] * rsqrtf(vo[c] + 1e-5f);
        float to = beo[c] - mo[c] * so;
        sc[j] = si * so;
        sh[j] = ti * so + to;
    }
#pragma unroll
    for (int i = 0; i < 4; ++i) {
        int grow = row0 + 4 * tr + i;
        if (grow >= N) continue;
        float y0 = fmaxf(u[i][0] * sc[0] + sh[0], 0.f);
        float y1 = fmaxf(u[i][1] * sc[1] + sh[1], 0.f);
        float y2 = fmaxf(u[i][2] * sc[2] + sh[2], 0.f);
        float y3 = fmaxf(u[i][3] * sc[3] + sh[3], 0.f);
        if (OUTB) {
            uint2 w;
            w.x = bf16pack(y0, y1);
            w.y = bf16pack(y2, y3);
            *reinterpret_cast<uint2*>(outb + (size_t)grow * 32 + tc * 2) = w;
        } else {
            float4 w = make_float4(y0, y1, y2, y3);
            *reinterpret_cast<float4*>(outf + (size_t)grow * 64 + 4 * tc) = w;
        }
    }
}

__device__ __forceinline__ int lbound(const int* __restrict__ a, int n, int v) {
    int lo = 0, hi = n;
    while (lo < hi) {
        int mid = (lo + hi) >> 1;
        if (a[mid] < v) lo = mid + 1;
        else hi = mid;
    }
    return lo;
}

// ---- per-graph mean -------------------------------------------------------
__global__ __launch_bounds__(256) void graph_mean(const float* __restrict__ H,
                                                  const int* __restrict__ gid,
                                                  int N,
                                                  float* __restrict__ hg) {
    __shared__ float part[4][64];
    const int g = blockIdx.x;
    const int lane = threadIdx.x & 63;
    const int w = threadIdx.x >> 6;
    const int lo = lbound(gid, N, g);
    const int hi = lbound(gid, N, g + 1);
    float acc = 0.f;
    for (int r = lo + w; r < hi; r += 4) acc += H[(size_t)r * 64 + lane];
    part[w][lane] = acc;
    __syncthreads();
    if (w == 0) {
        float s = part[0][lane] + part[1][lane] + part[2][lane] + part[3][lane];
        float cnt = fmaxf((float)(hi - lo), 1.0f);
        hg[(size_t)g * 64 + lane] = s / cnt;
    }
}

// ---- readout MLP ------------------------------------------------------------
__global__ __launch_bounds__(256) void readout_mlp(
    const float* __restrict__ hg, int G,
    const float* __restrict__ W1, const float* __restrict__ b1,
    const float* __restrict__ W2, const float* __restrict__ b2,
    float* __restrict__ out) {
    constexpr int PITCH = 68;
    __shared__ __align__(16) float Ws1[64 * 64];
    __shared__ __align__(16) float Ws2[64 * 64];
    __shared__ __align__(16) float Xs[64 * PITCH];
    __shared__ __align__(16) float Ys[64 * PITCH];

    const int t = threadIdx.x;
    const int row0 = blockIdx.x * 64;

#pragma unroll
    for (int j = 0; j < 4; ++j) {
        int f4 = t + 256 * j;
        reinterpret_cast<float4*>(Ws1)[f4] = reinterpret_cast<const float4*>(W1)[f4];
        reinterpret_cast<float4*>(Ws2)[f4] = reinterpret_cast<const float4*>(W2)[f4];
    }
    {
        int rs = t >> 2;
        int kq = t & 3;
        int grow = row0 + rs;
#pragma unroll
        for (int j = 0; j < 4; ++j) {
            int cf4 = kq + 4 * j;
            float4 v = make_float4(0.f, 0.f, 0.f, 0.f);
            if (grow < G)
                v = *reinterpret_cast<const float4*>(hg + (size_t)grow * 64 + cf4 * 4);
            int kb = cf4 * 4;
            Xs[(kb + 0) * PITCH + rs] = v.x;
            Xs[(kb + 1) * PITCH + rs] = v.y;
            Xs[(kb + 2) * PITCH + rs] = v.z;
            Xs[(kb + 3) * PITCH + rs] = v.w;
        }
    }
    __syncthreads();

    const int tr = t >> 4;
    const int tc = t & 15;

    float acc[4][4];
#pragma unroll
    for (int i = 0; i < 4; ++i)
#pragma unroll
        for (int j = 0; j < 4; ++j) acc[i][j] = 0.f;
#pragma unroll 4
    for (int k = 0; k < 64; ++k) {
        float4 a = *reinterpret_cast<const float4*>(&Xs[k * PITCH + 4 * tr]);
        float4 b = *reinterpret_cast<const float4*>(&Ws1[k * 64 + 4 * tc]);
        float av[4] = {a.x, a.y, a.z, a.w};
        float bv[4] = {b.x, b.y, b.z, b.w};
#pragma unroll
        for (int i = 0; i < 4; ++i)
#pragma unroll
            for (int j = 0; j < 4; ++j) acc[i][j] = fmaf(av[i], bv[j], acc[i][j]);
    }
    float u[4][4];
#pragma unroll
    for (int i = 0; i < 4; ++i)
#pragma unroll
        for (int j = 0; j < 4; ++j)
            u[i][j] = fmaxf(acc[i][j] + b1[4 * tc + j], 0.f);

#pragma unroll
    for (int j = 0; j < 4; ++j) {
        float4 w = make_float4(u[0][j], u[1][j], u[2][j], u[3][j]);
        *reinterpret_cast<float4*>(&Ys[(4 * tc + j) * PITCH + 4 * tr]) = w;
    }
    __syncthreads();
#pragma unroll
    for (int i = 0; i < 4; ++i)
#pragma unroll
        for (int j = 0; j < 4; ++j) acc[i][j] = 0.f;
#pragma unroll 4
    for (int k = 0; k < 64; ++k) {
        float4 a = *reinterpret_cast<const float4*>(&Ys[k * PITCH + 4 * tr]);
        float4 b = *reinterpret_cast<const float4*>(&Ws2[k * 64 + 4 * tc]);
        float av[4] = {a.x, a.y, a.z, a.w};
        float bv[4] = {b.x, b.y, b.z, b.w};
#pragma unroll
        for (int i = 0; i < 4; ++i)
#pragma unroll
            for (int j = 0; j < 4; ++j) acc[i][j] = fmaf(av[i], bv[j], acc[i][j]);
    }
#pragma unroll
    for (int i = 0; i < 4; ++i) {
        int grow = row0 + 4 * tr + i;
        if (grow >= G) continue;
        float4 w;
        w.x = acc[i][0] + b2[4 * tc + 0];
        w.y = acc[i][1] + b2[4 * tc + 1];
        w.z = acc[i][2] + b2[4 * tc + 2];
        w.w = acc[i][3] + b2[4 * tc + 3];
        *reinterpret_cast<float4*>(out + (size_t)grow * 64 + 4 * tc) = w;
    }
}

extern "C" void kernel_launch(void* const* d_in, const int* in_sizes, int n_in,
                              void* d_out, int out_size, void* d_ws, size_t ws_size,
                              hipStream_t stream) {
    const float* x    = (const float*)d_in[0];
    const int*   src  = (const int*)d_in[1];
    const int*   dst  = (const int*)d_in[2];
    const int*   gid  = (const int*)d_in[3];
    const float* eps0 = (const float*)d_in[4];
    const float* W0a  = (const float*)d_in[5];
    const float* bb0a = (const float*)d_in[6];
    const float* W0b  = (const float*)d_in[7];
    const float* bb0b = (const float*)d_in[8];
    const float* g0i  = (const float*)d_in[9];
    const float* be0i = (const float*)d_in[10];
    const float* m0i  = (const float*)d_in[11];
    const float* v0i  = (const float*)d_in[12];
    const float* g0   = (const float*)d_in[13];
    const float* be0  = (const float*)d_in[14];
    const float* m0   = (const float*)d_in[15];
    const float* v0   = (const float*)d_in[16];
    const float* eps1 = (const float*)d_in[17];
    const float* W1a  = (const float*)d_in[18];
    const float* bb1a = (const float*)d_in[19];
    const float* g1i  = (const float*)d_in[20];
    const float* be1i = (const float*)d_in[21];
    const float* m1i  = (const float*)d_in[22];
    const float* v1i  = (const float*)d_in[23];
    const float* g1   = (const float*)d_in[24];
    const float* be1  = (const float*)d_in[25];
    const float* m1   = (const float*)d_in[26];
    const float* v1   = (const float*)d_in[27];
    const float* Wr1  = (const float*)d_in[28];
    const float* br1  = (const float*)d_in[29];
    const float* Wr2  = (const float*)d_in[30];
    const float* br2  = (const float*)d_in[31];

    const int N = in_sizes[0] / 64;       // 50000
    const int E = in_sizes[1];            // 800000
    const int G = out_size / 64 - N;      // 500
    const int NB = (N + 127) >> 7;

    // ws layout
    char* ws = (char*)d_ws;
    unsigned* xb      = (unsigned*)ws;     ws += (size_t)N * 32 * 4;
    unsigned* Ab      = (unsigned*)ws;     ws += (size_t)N * 32 * 4;
    unsigned* Z0b     = (unsigned*)ws;     ws += (size_t)N * 32 * 4;
    unsigned* Bb      = (unsigned*)ws;     ws += (size_t)N * 32 * 4;
    int*      row_ptr = (int*)ws;          ws += ((size_t)N + 8) * 4;
    int*      ebase   = (int*)ws;          ws += (MAXB + 4) * 4;
    int*      cursor  = (int*)ws;          ws += (MAXB + 4) * 4;
    int*      ghist   = (int*)ws;          ws += (MAXB + 4) * 4;
    unsigned* ebuf    = (unsigned*)ws;     ws += (size_t)E * 4;
    float*    hg      = (float*)ws;        // G*64

    float* OUT = (float*)d_out;
    float* H   = OUT + (size_t)G * 64;

    const int EB = (E + EPB - 1) / EPB;
    const int NQ = N * 8;

    // ---- cast x->bf16 + zero hist ----
    cast_zero<<<(NQ + 255) / 256, 256, 0, stream>>>(
        (uint4*)xb, (const float4*)x, NQ, ghist);

    // ---- build CSR (bucketed; shared by both layers) ----
    bucket_hist<<<EB, 256, 0, stream>>>(ghist, dst, E);
    scan_small<<<1, 1024, 0, stream>>>(ghist, ebase, cursor, NB, E);
    bin_scatter<<<EB, 256, 0, stream>>>(ebuf, cursor, src, dst, E);
    bucket_fill<<<NB, 256, 0, stream>>>(ebuf, ebase, row_ptr, N, E);

    // ---- GIN layer 0 ----
    aggregate_bf16<<<(N + 3) / 4, 256, 0, stream>>>(Ab, xb, row_ptr, ebuf, eps0, N);
    mlp_fused<true, true><<<(N + 63) / 64, 256, 0, stream>>>(
        Ab, Z0b, nullptr, N, W0a, bb0a, W0b, bb0b,
        g0i, be0i, m0i, v0i, g0, be0, m0, v0);

    // ---- GIN layer 1 ----
    aggregate_bf16<<<(N + 3) / 4, 256, 0, stream>>>(Bb, Z0b, row_ptr, ebuf, eps1, N);
    mlp_fused<false, false><<<(N + 63) / 64, 256, 0, stream>>>(
        Bb, nullptr, H, N, W1a, bb1a, nullptr, nullptr,
        g1i, be1i, m1i, v1i, g1, be1, m1, v1);

    // ---- readout ----
    graph_mean<<<G, 256, 0, stream>>>(H, gid, N, hg);
    readout_mlp<<<(G + 63) / 64, 256, 0, stream>>>(hg, G, Wr1, br1, Wr2, br2, OUT);
}